// Round 1
// baseline (1003.123 us; speedup 1.0000x reference)
//
#include <hip/hip_runtime.h>

// GraphSeparableConv: Chebyshev(K=5) graph conv, depthwise + pointwise, fused.
// Layouts: T_k, acc as [M, C] with C = N*Fin = 512 (node-major, 2KB/node).
// Workspace: T0 | T1 | acc | row_ptr | fill | scol | sval  (~305 MB).

#define M_NODES 49152
#define FIN 32
#define KCH 5
#define FOUT 64

typedef float2 f2;

__global__ void count_kernel(const int* __restrict__ rows, int* __restrict__ cnt, int E) {
    int e = blockIdx.x * 256 + threadIdx.x;
    if (e < E) atomicAdd(&cnt[rows[e]], 1);
}

// Single-block exclusive scan over M counts -> row_ptr[M+1]; also re-inits
// cf[] to row_ptr values (scatter cursors). 1024 threads, wave-shfl based.
__global__ void scan_kernel(int* __restrict__ cf, int* __restrict__ row_ptr, int M) {
    int tid = threadIdx.x;
    int lane = tid & 63;
    int wid = tid >> 6;
    __shared__ int wsum[16];
    __shared__ int chunk_total;
    int carry = 0;
    for (int base = 0; base < M; base += 1024) {
        int i = base + tid;
        int v = (i < M) ? cf[i] : 0;
        int x = v;
        #pragma unroll
        for (int off = 1; off < 64; off <<= 1) {
            int y = __shfl_up(x, off, 64);
            if (lane >= off) x += y;
        }
        if (lane == 63) wsum[wid] = x;
        __syncthreads();
        if (tid < 16) {
            int w = wsum[tid];
            int xx = w;
            #pragma unroll
            for (int off = 1; off < 16; off <<= 1) {
                int y = __shfl_up(xx, off, 64);
                if (tid >= off) xx += y;
            }
            wsum[tid] = xx - w;       // exclusive prefix of wave sums
            if (tid == 15) chunk_total = xx;
        }
        __syncthreads();
        int pos = carry + (x - v) + wsum[wid];
        if (i < M) { row_ptr[i] = pos; cf[i] = pos; }
        carry += chunk_total;
        __syncthreads();
    }
    if (tid == 0) row_ptr[M] = carry;
}

__global__ void scatter_kernel(const int* __restrict__ rows, const int* __restrict__ cols,
                               const float* __restrict__ vals, int* __restrict__ fill,
                               int* __restrict__ scol, float* __restrict__ sval, int E) {
    int e = blockIdx.x * 256 + threadIdx.x;
    if (e < E) {
        int r = rows[e];
        int pos = atomicAdd(&fill[r], 1);
        scol[pos] = cols[e];
        sval[pos] = vals[e];
    }
}

// x [N,M,Fin] -> T0 [M, C] (C=N*Fin), and acc = dk[:,0] * T0 (Chebyshev T_0 term).
__global__ void transpose_init_kernel(const float* __restrict__ x, const float* __restrict__ dk,
                                      float* __restrict__ T0, float* __restrict__ acc,
                                      int M, int C) {
    int m = blockIdx.x;
    int t = threadIdx.x;
    int c0 = 2 * t;
    int n = c0 >> 5;
    int f0 = c0 & 31;
    f2 v = *(const f2*)(x + ((size_t)n * M + m) * FIN + f0);
    size_t o = (size_t)m * C + c0;
    *(f2*)(T0 + o) = v;
    f2 a;
    a.x = dk[f0 * KCH] * v.x;
    a.y = dk[(f0 + 1) * KCH] * v.y;
    *(f2*)(acc + o) = a;
}

// One block per row m. T_k = (first ? L*Tin : 2*L*Tin - Tout), written over Tout
// (which holds T_{k-2}); acc += dk[f,k] * T_k.
__global__ void spmm_cheb_kernel(const float* __restrict__ Tin, float* __restrict__ Tout,
                                 const int* __restrict__ row_ptr, const int* __restrict__ scol,
                                 const float* __restrict__ sval, float* __restrict__ acc,
                                 const float* __restrict__ dk, int k, int first, int C) {
    int m = blockIdx.x;
    int t = threadIdx.x;
    int c0 = 2 * t;
    int s = row_ptr[m];
    int e_end = row_ptr[m + 1];
    float sx = 0.f, sy = 0.f;
    for (int e = s; e < e_end; ++e) {
        float v = sval[e];
        int col = scol[e];
        f2 d = *(const f2*)(Tin + (size_t)col * C + c0);
        sx = fmaf(v, d.x, sx);
        sy = fmaf(v, d.y, sy);
    }
    size_t o = (size_t)m * C + c0;
    float rx, ry;
    if (first) {
        rx = sx; ry = sy;
    } else {
        f2 p = *(const f2*)(Tout + o);
        rx = 2.f * sx - p.x;
        ry = 2.f * sy - p.y;
    }
    f2 r; r.x = rx; r.y = ry;
    *(f2*)(Tout + o) = r;
    int f0 = c0 & 31;
    f2 a = *(const f2*)(acc + o);
    a.x = fmaf(dk[f0 * KCH + k], rx, a.x);
    a.y = fmaf(dk[(f0 + 1) * KCH + k], ry, a.y);
    *(f2*)(acc + o) = a;
}

// out[n,m,fo] = relu(bias[fo] + sum_f pk[fo,f] * acc[m, n*32+f])
// grid: (M/32, N); block 256 = 4 rows x 64 fo-lanes; 8 row-iterations per block.
__global__ __launch_bounds__(256) void pointwise_kernel(
    const float* __restrict__ acc, const float* __restrict__ pk,
    const float* __restrict__ bias, float* __restrict__ out, int M, int C) {
    int n = blockIdx.y;
    int m0 = blockIdx.x * 32;
    int sub = threadIdx.x >> 6;
    int fo = threadIdx.x & 63;
    float pkr[FIN];
    #pragma unroll
    for (int f = 0; f < FIN; ++f) pkr[f] = pk[fo * FIN + f];
    float b = bias[fo];
    __shared__ float accs[4][FIN];
    for (int it = 0; it < 8; ++it) {
        int m = m0 + it * 4 + sub;
        __syncthreads();
        if (fo < FIN) accs[sub][fo] = acc[(size_t)m * C + n * FIN + fo];
        __syncthreads();
        float ss = b;
        #pragma unroll
        for (int f = 0; f < FIN; ++f) ss = fmaf(pkr[f], accs[sub][f], ss);
        out[((size_t)n * M + m) * FOUT + fo] = fmaxf(ss, 0.f);
    }
}

extern "C" void kernel_launch(void* const* d_in, const int* in_sizes, int n_in,
                              void* d_out, int out_size, void* d_ws, size_t ws_size,
                              hipStream_t stream) {
    const float* x         = (const float*)d_in[0];
    const float* edge_vals = (const float*)d_in[1];
    const float* dk        = (const float*)d_in[2];
    const float* pk        = (const float*)d_in[3];
    const float* bias      = (const float*)d_in[4];
    const int*   erow      = (const int*)d_in[5];
    const int*   ecol      = (const int*)d_in[6];
    float* out = (float*)d_out;

    const int M = M_NODES;
    const int N = in_sizes[0] / (M * FIN);
    const int E = in_sizes[1];
    const int C = N * FIN;  // 512

    size_t SZ = (size_t)M * C;  // floats per T buffer
    float* T0      = (float*)d_ws;
    float* T1      = T0 + SZ;
    float* acc     = T1 + SZ;
    int*   row_ptr = (int*)(acc + SZ);
    int*   fill    = row_ptr + (M + 1);
    int*   scol    = fill + M;
    float* sval    = (float*)(scol + E);

    // CSR build (per call; no cached state)
    hipMemsetAsync(fill, 0, (size_t)M * sizeof(int), stream);
    count_kernel<<<(E + 255) / 256, 256, 0, stream>>>(erow, fill, E);
    scan_kernel<<<1, 1024, 0, stream>>>(fill, row_ptr, M);
    scatter_kernel<<<(E + 255) / 256, 256, 0, stream>>>(erow, ecol, edge_vals, fill, scol, sval, E);

    // T0 = x^T, acc = dk[:,0]*T0
    transpose_init_kernel<<<M, C / 2, 0, stream>>>(x, dk, T0, acc, M, C);

    // Chebyshev recursion, depthwise-accumulated
    spmm_cheb_kernel<<<M, C / 2, 0, stream>>>(T0, T1, row_ptr, scol, sval, acc, dk, 1, 1, C);
    spmm_cheb_kernel<<<M, C / 2, 0, stream>>>(T1, T0, row_ptr, scol, sval, acc, dk, 2, 0, C);
    spmm_cheb_kernel<<<M, C / 2, 0, stream>>>(T0, T1, row_ptr, scol, sval, acc, dk, 3, 0, C);
    spmm_cheb_kernel<<<M, C / 2, 0, stream>>>(T1, T0, row_ptr, scol, sval, acc, dk, 4, 0, C);

    // Pointwise GEMM + bias + relu
    dim3 pgrid(M / 32, N);
    pointwise_kernel<<<pgrid, 256, 0, stream>>>(acc, pk, bias, out, M, C);
}

// Round 2
// 727.589 us; speedup vs baseline: 1.3787x; 1.3787x over previous
//
#include <hip/hip_runtime.h>

// GraphSeparableConv: Chebyshev(K=5) graph conv, depthwise + pointwise.
// Round 2: bf16 T-buffers (halve gather traffic), fused cast-transpose,
// pointwise epilogue fused into the last SpMM.
// Layouts: T_k as [M, C] bf16 packed pairs (C = N*Fin = 512), acc [M, C] f32.

#define M_NODES 49152
#define FIN 32
#define KCH 5
#define FOUT 64
#define NB 16

typedef unsigned int u32;
typedef float2 f2;

__device__ __forceinline__ float bflo(u32 w) { union { float f; u32 i; } v; v.i = w << 16; return v.f; }
__device__ __forceinline__ float bfhi(u32 w) { union { float f; u32 i; } v; v.i = w & 0xffff0000u; return v.f; }
__device__ __forceinline__ u32 f2bf(float f) {
    union { float f; u32 i; } v; v.f = f;
    u32 r = v.i + 0x7fffu + ((v.i >> 16) & 1u);
    return r >> 16;
}

__global__ void count_kernel(const int* __restrict__ rows, int* __restrict__ cnt, int E) {
    int e = blockIdx.x * 256 + threadIdx.x;
    if (e < E) atomicAdd(&cnt[rows[e]], 1);
}

// Single-block exclusive scan over M counts -> row_ptr[M+1]; re-inits cf[] to
// row_ptr values (scatter cursors).
__global__ void scan_kernel(int* __restrict__ cf, int* __restrict__ row_ptr, int M) {
    int tid = threadIdx.x;
    int lane = tid & 63;
    int wid = tid >> 6;
    __shared__ int wsum[16];
    __shared__ int chunk_total;
    int carry = 0;
    for (int base = 0; base < M; base += 1024) {
        int i = base + tid;
        int v = (i < M) ? cf[i] : 0;
        int x = v;
        #pragma unroll
        for (int off = 1; off < 64; off <<= 1) {
            int y = __shfl_up(x, off, 64);
            if (lane >= off) x += y;
        }
        if (lane == 63) wsum[wid] = x;
        __syncthreads();
        if (tid < 16) {
            int w = wsum[tid];
            int xx = w;
            #pragma unroll
            for (int off = 1; off < 16; off <<= 1) {
                int y = __shfl_up(xx, off, 64);
                if (tid >= off) xx += y;
            }
            wsum[tid] = xx - w;
            if (tid == 15) chunk_total = xx;
        }
        __syncthreads();
        int pos = carry + (x - v) + wsum[wid];
        if (i < M) { row_ptr[i] = pos; cf[i] = pos; }
        carry += chunk_total;
        __syncthreads();
    }
    if (tid == 0) row_ptr[M] = carry;
}

__global__ void scatter_kernel(const int* __restrict__ rows, const int* __restrict__ cols,
                               const float* __restrict__ vals, int* __restrict__ fill,
                               int* __restrict__ scol, float* __restrict__ sval, int E) {
    int e = blockIdx.x * 256 + threadIdx.x;
    if (e < E) {
        int r = rows[e];
        int pos = atomicAdd(&fill[r], 1);
        scol[pos] = cols[e];
        sval[pos] = vals[e];
    }
}

// x [N,M,Fin] f32 -> T0 [M, C] bf16-packed
__global__ __launch_bounds__(256) void cast_transpose_kernel(
    const float* __restrict__ x, u32* __restrict__ T0, int M) {
    int m = blockIdx.x;
    int t = threadIdx.x;
    int c0 = 2 * t;
    int n = c0 >> 5;
    int f0 = c0 & 31;
    f2 v = *(const f2*)(x + ((size_t)n * M + m) * FIN + f0);
    T0[(size_t)m * 256 + t] = f2bf(v.x) | (f2bf(v.y) << 16);
}

// One block per row m, 256 threads, 2 channels/thread (packed bf16).
// FIRST (k=1): r = L*T0; acc = dk0*T0 + dk1*r (write, no read).
// middle:      r = 2*L*Tin - Tprev; acc += dk_k*r (RMW); Tout[m] = r.
// LAST (k=4):  r as middle; a = acc + dk4*r; no T/acc write; fused
//              pointwise epilogue: out[n,m,fo] = relu(bias + pk @ a_row).
template<int FIRST, int LAST>
__global__ __launch_bounds__(256) void spmm_cheb_kernel(
    const u32* __restrict__ Tin, const u32* __restrict__ Tprev, u32* __restrict__ Tout,
    const int* __restrict__ row_ptr, const int* __restrict__ scol,
    const float* __restrict__ sval, float* __restrict__ acc,
    const float* __restrict__ dk, const float* __restrict__ pk,
    const float* __restrict__ bias, float* __restrict__ out, int k, int M) {
    int m = blockIdx.x;
    int t = threadIdx.x;
    int c0 = 2 * t;
    int f0 = c0 & 31;
    int s = row_ptr[m];
    int e_end = row_ptr[m + 1];
    float sx = 0.f, sy = 0.f;
    for (int e = s; e < e_end; ++e) {
        float v = sval[e];
        u32 w = Tin[(size_t)scol[e] * 256 + t];
        sx = fmaf(v, bflo(w), sx);
        sy = fmaf(v, bfhi(w), sy);
    }
    u32 pw = Tprev[(size_t)m * 256 + t];
    float px = bflo(pw), py = bfhi(pw);
    size_t o = (size_t)m * 512 + c0;
    float rx, ry, ax, ay;
    if (FIRST) {
        rx = sx; ry = sy;
        ax = fmaf(dk[f0 * KCH], px, dk[f0 * KCH + 1] * rx);
        ay = fmaf(dk[(f0 + 1) * KCH], py, dk[(f0 + 1) * KCH + 1] * ry);
    } else {
        rx = fmaf(2.f, sx, -px);
        ry = fmaf(2.f, sy, -py);
        f2 ap = *(const f2*)(acc + o);
        ax = fmaf(dk[f0 * KCH + k], rx, ap.x);
        ay = fmaf(dk[(f0 + 1) * KCH + k], ry, ap.y);
    }
    if (!LAST) {
        Tout[(size_t)m * 256 + t] = f2bf(rx) | (f2bf(ry) << 16);
        f2 a; a.x = ax; a.y = ay;
        *(f2*)(acc + o) = a;
    } else {
        __shared__ float arow[512];
        arow[c0] = ax;
        arow[c0 + 1] = ay;
        __syncthreads();
        int fo = t & 63;
        int w = t >> 6;
        float pkr[FIN];
        const float4* pk4 = (const float4*)(pk + fo * FIN);
        #pragma unroll
        for (int f4 = 0; f4 < 8; ++f4) {
            float4 p = pk4[f4];
            pkr[4 * f4 + 0] = p.x; pkr[4 * f4 + 1] = p.y;
            pkr[4 * f4 + 2] = p.z; pkr[4 * f4 + 3] = p.w;
        }
        float b = bias[fo];
        #pragma unroll
        for (int it = 0; it < 4; ++it) {
            int n = it * 4 + w;
            const float4* ar4 = (const float4*)(arow + n * FIN);
            float ss = b;
            #pragma unroll
            for (int f4 = 0; f4 < 8; ++f4) {
                float4 a4 = ar4[f4];
                ss = fmaf(pkr[4 * f4 + 0], a4.x, ss);
                ss = fmaf(pkr[4 * f4 + 1], a4.y, ss);
                ss = fmaf(pkr[4 * f4 + 2], a4.z, ss);
                ss = fmaf(pkr[4 * f4 + 3], a4.w, ss);
            }
            out[((size_t)n * M + m) * FOUT + fo] = fmaxf(ss, 0.f);
        }
    }
}

extern "C" void kernel_launch(void* const* d_in, const int* in_sizes, int n_in,
                              void* d_out, int out_size, void* d_ws, size_t ws_size,
                              hipStream_t stream) {
    const float* x         = (const float*)d_in[0];
    const float* edge_vals = (const float*)d_in[1];
    const float* dk        = (const float*)d_in[2];
    const float* pk        = (const float*)d_in[3];
    const float* bias      = (const float*)d_in[4];
    const int*   erow      = (const int*)d_in[5];
    const int*   ecol      = (const int*)d_in[6];
    float* out = (float*)d_out;

    const int M = M_NODES;
    const int E = in_sizes[1];
    const int C = NB * FIN;  // 512

    size_t SZP = (size_t)M * (C / 2);  // u32 words per packed-bf16 T buffer
    u32*   Ta      = (u32*)d_ws;
    u32*   Tb      = Ta + SZP;
    float* acc     = (float*)(Tb + SZP);
    int*   row_ptr = (int*)(acc + (size_t)M * C);
    int*   fill    = row_ptr + (M + 1);
    int*   scol    = fill + M;
    float* sval    = (float*)(scol + E);

    // CSR build (per call; no cached state)
    hipMemsetAsync(fill, 0, (size_t)M * sizeof(int), stream);
    count_kernel<<<(E + 255) / 256, 256, 0, stream>>>(erow, fill, E);
    scan_kernel<<<1, 1024, 0, stream>>>(fill, row_ptr, M);
    scatter_kernel<<<(E + 255) / 256, 256, 0, stream>>>(erow, ecol, edge_vals, fill, scol, sval, E);

    // Ta = T0 = x^T (bf16)
    cast_transpose_kernel<<<M, 256, 0, stream>>>(x, Ta, M);

    // k=1: Tb = T1 = L*T0; acc = dk0*T0 + dk1*T1
    spmm_cheb_kernel<1, 0><<<M, 256, 0, stream>>>(Ta, Ta, Tb, row_ptr, scol, sval,
                                                  acc, dk, pk, bias, out, 1, M);
    // k=2: Ta <- T2 = 2L*T1 - T0; acc += dk2*T2
    spmm_cheb_kernel<0, 0><<<M, 256, 0, stream>>>(Tb, Ta, Ta, row_ptr, scol, sval,
                                                  acc, dk, pk, bias, out, 2, M);
    // k=3: Tb <- T3 = 2L*T2 - T1; acc += dk3*T3
    spmm_cheb_kernel<0, 0><<<M, 256, 0, stream>>>(Ta, Tb, Tb, row_ptr, scol, sval,
                                                  acc, dk, pk, bias, out, 3, M);
    // k=4: T4 = 2L*T3 - T2 (not stored); a = acc + dk4*T4; fused pointwise+bias+relu
    spmm_cheb_kernel<0, 1><<<M, 256, 0, stream>>>(Tb, Ta, (u32*)nullptr, row_ptr, scol, sval,
                                                  acc, dk, pk, bias, out, 4, M);
}

// Round 3
// 551.622 us; speedup vs baseline: 1.8185x; 1.3190x over previous
//
#include <hip/hip_runtime.h>

// GraphSeparableConv round 3:
//  - acc eliminated: out = sum_k W_k @ T_k, W_k[fo,f] = pk[fo,f]*dk[f,k]
//  - SpMM = pure Chebyshev recurrence over bf16 T buffers (wave per row,
//    uint4 gathers: 1KB per edge per wave)
//  - final pass: bf16 MFMA GEMM [N*M x 160] x [160 x 64] + bias + relu
// T_k layout: [M][512] bf16 (1KB rows), five buffers contiguous in ws.

#define M_NODES 49152
#define FIN 32
#define KCH 5
#define FOUT 64
#define NB 16

typedef unsigned int u32;
typedef unsigned short u16;
typedef short bf16x8 __attribute__((ext_vector_type(8)));
typedef float f32x4 __attribute__((ext_vector_type(4)));

__device__ __forceinline__ float bflo(u32 w) { union { float f; u32 i; } v; v.i = w << 16; return v.f; }
__device__ __forceinline__ float bfhi(u32 w) { union { float f; u32 i; } v; v.i = w & 0xffff0000u; return v.f; }
__device__ __forceinline__ u32 f2bf(float f) {
    union { float f; u32 i; } v; v.f = f;
    u32 r = v.i + 0x7fffu + ((v.i >> 16) & 1u);
    return r >> 16;
}
__device__ __forceinline__ u32 pack2(float a, float b) { return f2bf(a) | (f2bf(b) << 16); }

__global__ void count_kernel(const int* __restrict__ rows, int* __restrict__ cnt, int E) {
    int e = blockIdx.x * 256 + threadIdx.x;
    if (e < E) atomicAdd(&cnt[rows[e]], 1);
}

// Single-block exclusive scan over M counts -> row_ptr[M+1]; re-inits cf[] to
// row_ptr values (scatter cursors).
__global__ void scan_kernel(int* __restrict__ cf, int* __restrict__ row_ptr, int M) {
    int tid = threadIdx.x;
    int lane = tid & 63;
    int wid = tid >> 6;
    __shared__ int wsum[16];
    __shared__ int chunk_total;
    int carry = 0;
    for (int base = 0; base < M; base += 1024) {
        int i = base + tid;
        int v = (i < M) ? cf[i] : 0;
        int x = v;
        #pragma unroll
        for (int off = 1; off < 64; off <<= 1) {
            int y = __shfl_up(x, off, 64);
            if (lane >= off) x += y;
        }
        if (lane == 63) wsum[wid] = x;
        __syncthreads();
        if (tid < 16) {
            int w = wsum[tid];
            int xx = w;
            #pragma unroll
            for (int off = 1; off < 16; off <<= 1) {
                int y = __shfl_up(xx, off, 64);
                if (tid >= off) xx += y;
            }
            wsum[tid] = xx - w;
            if (tid == 15) chunk_total = xx;
        }
        __syncthreads();
        int pos = carry + (x - v) + wsum[wid];
        if (i < M) { row_ptr[i] = pos; cf[i] = pos; }
        carry += chunk_total;
        __syncthreads();
    }
    if (tid == 0) row_ptr[M] = carry;
}

__global__ void scatter_kernel(const int* __restrict__ rows, const int* __restrict__ cols,
                               const float* __restrict__ vals, int* __restrict__ fill,
                               int2* __restrict__ edges, int E) {
    int e = blockIdx.x * 256 + threadIdx.x;
    if (e < E) {
        int r = rows[e];
        int pos = atomicAdd(&fill[r], 1);
        int2 ed; ed.x = cols[e]; ed.y = __float_as_int(vals[e]);
        edges[pos] = ed;
    }
}

// x [N,M,Fin] f32 -> T0 [M][512] bf16.  Wave per row; lane covers 8 channels.
__global__ __launch_bounds__(256) void cast_transpose_kernel(
    const float* __restrict__ x, uint4* __restrict__ T0, int M) {
    int m = blockIdx.x * 4 + (threadIdx.x >> 6);
    int l = threadIdx.x & 63;
    int n = l >> 2;
    int f0 = (l & 3) * 8;
    const float4* xp = (const float4*)(x + ((size_t)n * M + m) * FIN + f0);
    float4 a = xp[0], b = xp[1];
    uint4 o;
    o.x = pack2(a.x, a.y); o.y = pack2(a.z, a.w);
    o.z = pack2(b.x, b.y); o.w = pack2(b.z, b.w);
    T0[(size_t)m * 64 + l] = o;
}

// W[fo][k*32+f] = bf16(pk[fo,f] * dk[f,k]) : 64 x 160 bf16
__global__ void wprep_kernel(const float* __restrict__ dk, const float* __restrict__ pk,
                             u16* __restrict__ W) {
    int t = blockIdx.x * 256 + threadIdx.x;
    if (t < FOUT * KCH * FIN) {
        int fo = t / (KCH * FIN);
        int kf = t % (KCH * FIN);
        int kc = kf / FIN;
        int f  = kf % FIN;
        W[fo * (KCH * FIN) + kf] = (u16)f2bf(pk[fo * FIN + f] * dk[f * KCH + kc]);
    }
}

// Wave per row m. FIRST: T1 = L*T0.  else: T_k = 2*L*T_{k-1} - T_{k-2}.
template<int FIRST>
__global__ __launch_bounds__(256) void spmm_kernel(
    const uint4* __restrict__ Tin, const uint4* __restrict__ Tprev, uint4* __restrict__ Tout,
    const int* __restrict__ row_ptr, const int2* __restrict__ edges, int M) {
    int m = blockIdx.x * 4 + (threadIdx.x >> 6);
    int l = threadIdx.x & 63;
    int s = row_ptr[m];
    int e_end = row_ptr[m + 1];
    float r[8] = {0.f, 0.f, 0.f, 0.f, 0.f, 0.f, 0.f, 0.f};
    for (int e = s; e < e_end; ++e) {
        int2 ed = edges[e];
        float v = __int_as_float(ed.y);
        uint4 g = Tin[(size_t)ed.x * 64 + l];
        r[0] = fmaf(v, bflo(g.x), r[0]); r[1] = fmaf(v, bfhi(g.x), r[1]);
        r[2] = fmaf(v, bflo(g.y), r[2]); r[3] = fmaf(v, bfhi(g.y), r[3]);
        r[4] = fmaf(v, bflo(g.z), r[4]); r[5] = fmaf(v, bfhi(g.z), r[5]);
        r[6] = fmaf(v, bflo(g.w), r[6]); r[7] = fmaf(v, bfhi(g.w), r[7]);
    }
    if (!FIRST) {
        uint4 p = Tprev[(size_t)m * 64 + l];
        r[0] = fmaf(2.f, r[0], -bflo(p.x)); r[1] = fmaf(2.f, r[1], -bfhi(p.x));
        r[2] = fmaf(2.f, r[2], -bflo(p.y)); r[3] = fmaf(2.f, r[3], -bfhi(p.y));
        r[4] = fmaf(2.f, r[4], -bflo(p.z)); r[5] = fmaf(2.f, r[5], -bfhi(p.z));
        r[6] = fmaf(2.f, r[6], -bflo(p.w)); r[7] = fmaf(2.f, r[7], -bfhi(p.w));
    }
    uint4 o;
    o.x = pack2(r[0], r[1]); o.y = pack2(r[2], r[3]);
    o.z = pack2(r[4], r[5]); o.w = pack2(r[6], r[7]);
    Tout[(size_t)m * 64 + l] = o;
}

// out[n,m,fo] = relu(bias[fo] + sum_{k,f} W[fo, k*32+f] * T_k[m, n*32+f])
// Block: 256 thr = 4 waves; block owns 16 m-rows x 64 fo; wave = one fo-tile.
// Per n: 5 chained mfma_f32_16x16x32_bf16 over the k-stack.
// A-frag: lane holds T_k[m0 + (l&15)][n*32 + (l>>4)*8 .. +7]  (one uint4).
// B-frag: lane holds W[fo0 + (l&15)][k*32 + (l>>4)*8 .. +7]   (one uint4).
// D: row = (l>>4)*4 + reg, col = l&15.
__global__ __launch_bounds__(256) void pw_mfma_kernel(
    const uint4* __restrict__ T, const uint4* __restrict__ W4,
    const float* __restrict__ bias, float* __restrict__ out, int M) {
    int wid = threadIdx.x >> 6;
    int l = threadIdx.x & 63;
    int lr = l & 15;
    int lg = l >> 4;
    int m0 = blockIdx.x * 16;
    int fo0 = wid * 16;

    bf16x8 bfr[KCH];
    #pragma unroll
    for (int kc = 0; kc < KCH; ++kc) {
        uint4 w = W4[(fo0 + lr) * 20 + kc * 4 + lg];
        bfr[kc] = *(bf16x8*)&w;
    }
    float bv = bias[fo0 + lr];
    size_t arow = (size_t)(m0 + lr) * 64 + lg;
    const size_t kstride = (size_t)M * 64;

    for (int n = 0; n < NB; ++n) {
        f32x4 acc = {bv, bv, bv, bv};
        #pragma unroll
        for (int kc = 0; kc < KCH; ++kc) {
            uint4 a = T[kc * kstride + arow + n * 4];
            acc = __builtin_amdgcn_mfma_f32_16x16x32_bf16(*(bf16x8*)&a, bfr[kc], acc, 0, 0, 0);
        }
        float* op = out + ((size_t)n * M + m0 + lg * 4) * FOUT + fo0 + lr;
        #pragma unroll
        for (int rr = 0; rr < 4; ++rr)
            op[(size_t)rr * FOUT] = fmaxf(acc[rr], 0.f);
    }
}

extern "C" void kernel_launch(void* const* d_in, const int* in_sizes, int n_in,
                              void* d_out, int out_size, void* d_ws, size_t ws_size,
                              hipStream_t stream) {
    const float* x         = (const float*)d_in[0];
    const float* edge_vals = (const float*)d_in[1];
    const float* dk        = (const float*)d_in[2];
    const float* pk        = (const float*)d_in[3];
    const float* bias      = (const float*)d_in[4];
    const int*   erow      = (const int*)d_in[5];
    const int*   ecol      = (const int*)d_in[6];
    float* out = (float*)d_out;

    const int M = M_NODES;
    const int E = in_sizes[1];

    // ws layout: 5 T buffers (bf16 [M][512]) | W | row_ptr | fill | edges
    size_t t_words = (size_t)M * 64;              // uint4 per T buffer
    uint4* T       = (uint4*)d_ws;                // T + k*t_words = T_k
    u16*   W       = (u16*)(T + 5 * t_words);
    int*   row_ptr = (int*)(W + FOUT * KCH * FIN);
    int*   fill    = row_ptr + (M + 1);
    int2*  edges   = (int2*)(fill + M);

    uint4* T0 = T;
    uint4* T1 = T + 1 * t_words;
    uint4* T2 = T + 2 * t_words;
    uint4* T3 = T + 3 * t_words;
    uint4* T4 = T + 4 * t_words;

    // CSR build (per call; no cached state)
    hipMemsetAsync(fill, 0, (size_t)M * sizeof(int), stream);
    count_kernel<<<(E + 255) / 256, 256, 0, stream>>>(erow, fill, E);
    scan_kernel<<<1, 1024, 0, stream>>>(fill, row_ptr, M);
    scatter_kernel<<<(E + 255) / 256, 256, 0, stream>>>(erow, ecol, edge_vals, fill, edges, E);

    // T0 = x^T (bf16); W = pk (*) dk
    cast_transpose_kernel<<<M / 4, 256, 0, stream>>>(x, T0, M);
    wprep_kernel<<<(FOUT * KCH * FIN + 255) / 256, 256, 0, stream>>>(dk, pk, W);

    // Chebyshev recursion
    spmm_kernel<1><<<M / 4, 256, 0, stream>>>(T0, T0, T1, row_ptr, edges, M);
    spmm_kernel<0><<<M / 4, 256, 0, stream>>>(T1, T0, T2, row_ptr, edges, M);
    spmm_kernel<0><<<M / 4, 256, 0, stream>>>(T2, T1, T3, row_ptr, edges, M);
    spmm_kernel<0><<<M / 4, 256, 0, stream>>>(T3, T2, T4, row_ptr, edges, M);

    // Fused depthwise+pointwise via MFMA, bias + relu epilogue
    pw_mfma_kernel<<<M / 16, 256, 0, stream>>>(T, (const uint4*)W, bias, out, M);
}

// Round 4
// 480.645 us; speedup vs baseline: 2.0870x; 1.1477x over previous
//
#include <hip/hip_runtime.h>

// GraphSeparableConv round 4:
//  - spmm: 4-wide edge unroll (4 outstanding gathers/wave, was 1)
//  - pw:   LDS-staged A-tiles (XOR-swizzled, double-buffered over kc),
//          waves split n, acc persists over kc, nontemporal out stores
// T_k layout: [M][512] bf16 (1KB rows), five buffers contiguous in ws.

#define M_NODES 49152
#define FIN 32
#define KCH 5
#define FOUT 64
#define NB 16

typedef unsigned int u32;
typedef unsigned short u16;
typedef short bf16x8 __attribute__((ext_vector_type(8)));
typedef float f32x4 __attribute__((ext_vector_type(4)));

__device__ __forceinline__ float bflo(u32 w) { union { float f; u32 i; } v; v.i = w << 16; return v.f; }
__device__ __forceinline__ float bfhi(u32 w) { union { float f; u32 i; } v; v.i = w & 0xffff0000u; return v.f; }
__device__ __forceinline__ u32 f2bf(float f) {
    union { float f; u32 i; } v; v.f = f;
    u32 r = v.i + 0x7fffu + ((v.i >> 16) & 1u);
    return r >> 16;
}
__device__ __forceinline__ u32 pack2(float a, float b) { return f2bf(a) | (f2bf(b) << 16); }

__global__ void count_kernel(const int* __restrict__ rows, int* __restrict__ cnt, int E) {
    int e = blockIdx.x * 256 + threadIdx.x;
    if (e < E) atomicAdd(&cnt[rows[e]], 1);
}

// Single-block exclusive scan over M counts -> row_ptr[M+1]; re-inits cf[] to
// row_ptr values (scatter cursors).
__global__ void scan_kernel(int* __restrict__ cf, int* __restrict__ row_ptr, int M) {
    int tid = threadIdx.x;
    int lane = tid & 63;
    int wid = tid >> 6;
    __shared__ int wsum[16];
    __shared__ int chunk_total;
    int carry = 0;
    for (int base = 0; base < M; base += 1024) {
        int i = base + tid;
        int v = (i < M) ? cf[i] : 0;
        int x = v;
        #pragma unroll
        for (int off = 1; off < 64; off <<= 1) {
            int y = __shfl_up(x, off, 64);
            if (lane >= off) x += y;
        }
        if (lane == 63) wsum[wid] = x;
        __syncthreads();
        if (tid < 16) {
            int w = wsum[tid];
            int xx = w;
            #pragma unroll
            for (int off = 1; off < 16; off <<= 1) {
                int y = __shfl_up(xx, off, 64);
                if (tid >= off) xx += y;
            }
            wsum[tid] = xx - w;
            if (tid == 15) chunk_total = xx;
        }
        __syncthreads();
        int pos = carry + (x - v) + wsum[wid];
        if (i < M) { row_ptr[i] = pos; cf[i] = pos; }
        carry += chunk_total;
        __syncthreads();
    }
    if (tid == 0) row_ptr[M] = carry;
}

__global__ void scatter_kernel(const int* __restrict__ rows, const int* __restrict__ cols,
                               const float* __restrict__ vals, int* __restrict__ fill,
                               int2* __restrict__ edges, int E) {
    int e = blockIdx.x * 256 + threadIdx.x;
    if (e < E) {
        int r = rows[e];
        int pos = atomicAdd(&fill[r], 1);
        int2 ed; ed.x = cols[e]; ed.y = __float_as_int(vals[e]);
        edges[pos] = ed;
    }
}

// x [N,M,Fin] f32 -> T0 [M][512] bf16.  Wave per row; lane covers 8 channels.
__global__ __launch_bounds__(256) void cast_transpose_kernel(
    const float* __restrict__ x, uint4* __restrict__ T0, int M) {
    int m = blockIdx.x * 4 + (threadIdx.x >> 6);
    int l = threadIdx.x & 63;
    int n = l >> 2;
    int f0 = (l & 3) * 8;
    const float4* xp = (const float4*)(x + ((size_t)n * M + m) * FIN + f0);
    float4 a = xp[0], b = xp[1];
    uint4 o;
    o.x = pack2(a.x, a.y); o.y = pack2(a.z, a.w);
    o.z = pack2(b.x, b.y); o.w = pack2(b.z, b.w);
    T0[(size_t)m * 64 + l] = o;
}

// W[fo][k*32+f] = bf16(pk[fo,f] * dk[f,k]) : 64 x 160 bf16
__global__ void wprep_kernel(const float* __restrict__ dk, const float* __restrict__ pk,
                             u16* __restrict__ W) {
    int t = blockIdx.x * 256 + threadIdx.x;
    if (t < FOUT * KCH * FIN) {
        int fo = t / (KCH * FIN);
        int kf = t % (KCH * FIN);
        int kc = kf / FIN;
        int f  = kf % FIN;
        W[fo * (KCH * FIN) + kf] = (u16)f2bf(pk[fo * FIN + f] * dk[f * KCH + kc]);
    }
}

__device__ __forceinline__ void acc8(float* r, uint4 g, float v) {
    r[0] = fmaf(v, bflo(g.x), r[0]); r[1] = fmaf(v, bfhi(g.x), r[1]);
    r[2] = fmaf(v, bflo(g.y), r[2]); r[3] = fmaf(v, bfhi(g.y), r[3]);
    r[4] = fmaf(v, bflo(g.z), r[4]); r[5] = fmaf(v, bfhi(g.z), r[5]);
    r[6] = fmaf(v, bflo(g.w), r[6]); r[7] = fmaf(v, bfhi(g.w), r[7]);
}

// Wave per row m, 4-wide edge unroll for memory-level parallelism.
// FIRST: T1 = L*T0.  else: T_k = 2*L*T_{k-1} - T_{k-2}.
template<int FIRST>
__global__ __launch_bounds__(256) void spmm_kernel(
    const uint4* __restrict__ Tin, const uint4* __restrict__ Tprev, uint4* __restrict__ Tout,
    const int* __restrict__ row_ptr, const int2* __restrict__ edges, int M) {
    int m = blockIdx.x * 4 + (threadIdx.x >> 6);
    int l = threadIdx.x & 63;
    int e = row_ptr[m];
    int e_end = row_ptr[m + 1];
    float r[8] = {0.f, 0.f, 0.f, 0.f, 0.f, 0.f, 0.f, 0.f};
    for (; e + 4 <= e_end; e += 4) {
        int2 e0 = edges[e], e1 = edges[e + 1], e2 = edges[e + 2], e3 = edges[e + 3];
        uint4 g0 = Tin[(size_t)e0.x * 64 + l];
        uint4 g1 = Tin[(size_t)e1.x * 64 + l];
        uint4 g2 = Tin[(size_t)e2.x * 64 + l];
        uint4 g3 = Tin[(size_t)e3.x * 64 + l];
        acc8(r, g0, __int_as_float(e0.y));
        acc8(r, g1, __int_as_float(e1.y));
        acc8(r, g2, __int_as_float(e2.y));
        acc8(r, g3, __int_as_float(e3.y));
    }
    for (; e < e_end; ++e) {
        int2 ed = edges[e];
        uint4 g = Tin[(size_t)ed.x * 64 + l];
        acc8(r, g, __int_as_float(ed.y));
    }
    if (!FIRST) {
        uint4 p = Tprev[(size_t)m * 64 + l];
        r[0] = fmaf(2.f, r[0], -bflo(p.x)); r[1] = fmaf(2.f, r[1], -bfhi(p.x));
        r[2] = fmaf(2.f, r[2], -bflo(p.y)); r[3] = fmaf(2.f, r[3], -bfhi(p.y));
        r[4] = fmaf(2.f, r[4], -bflo(p.z)); r[5] = fmaf(2.f, r[5], -bfhi(p.z));
        r[6] = fmaf(2.f, r[6], -bflo(p.w)); r[7] = fmaf(2.f, r[7], -bfhi(p.w));
    }
    uint4 o;
    o.x = pack2(r[0], r[1]); o.y = pack2(r[2], r[3]);
    o.z = pack2(r[4], r[5]); o.w = pack2(r[6], r[7]);
    Tout[(size_t)m * 64 + l] = o;
}

// out[n,m,fo] = relu(bias[fo] + sum_{k,f} W[fo, k*32+f] * T_k[m, n*32+f])
// Block: 256 thr = 4 waves; block owns m-tile of 16 rows x all 16 n x 64 fo.
// Per kc: stage T_kc[m0..m0+15][:] (16KB) in LDS (XOR swizzle, double buffer);
// wave w handles n = 4w..4w+3, 4 fo-tiles each; acc[4][4] f32x4 over kc.
// A-frag ds_read: lane(lr,lg) reads row lr, col16 (n*4+lg)^(lr&7) -> 2-way, free.
__global__ __launch_bounds__(256) void pw_mfma_kernel(
    const uint4* __restrict__ T, const uint4* __restrict__ W4,
    const float* __restrict__ bias, float* __restrict__ out, int M) {
    __shared__ uint4 lds[2][1024];
    int t = threadIdx.x;
    int w = t >> 6;
    int l = t & 63;
    int lr = l & 15;
    int lg = l >> 4;
    int m0 = blockIdx.x * 16;
    const size_t kstride = (size_t)M * 64;
    const uint4* tile_base = T + (size_t)m0 * 64;

    float bv[4];
    #pragma unroll
    for (int fo = 0; fo < 4; ++fo) bv[fo] = bias[fo * 16 + lr];

    f32x4 acc[4][4];
    #pragma unroll
    for (int nn = 0; nn < 4; ++nn)
        #pragma unroll
        for (int fo = 0; fo < 4; ++fo)
            acc[nn][fo] = (f32x4){bv[fo], bv[fo], bv[fo], bv[fo]};

    // prologue: stage kc=0
    uint4 sreg[4];
    #pragma unroll
    for (int j = 0; j < 4; ++j) sreg[j] = tile_base[(size_t)j * 256 + t];
    #pragma unroll
    for (int j = 0; j < 4; ++j) {
        int idx = j * 256 + t;
        int row = idx >> 6, c = idx & 63;
        lds[0][row * 64 + (c ^ (row & 7))] = sreg[j];
    }
    __syncthreads();

    for (int kc = 0; kc < KCH; ++kc) {
        uint4 nreg[4];
        if (kc < KCH - 1) {
            const uint4* src = tile_base + (size_t)(kc + 1) * kstride;
            #pragma unroll
            for (int j = 0; j < 4; ++j) nreg[j] = src[(size_t)j * 256 + t];
        }
        bf16x8 bfr[4];
        #pragma unroll
        for (int fo = 0; fo < 4; ++fo) {
            uint4 wv = W4[(fo * 16 + lr) * 20 + kc * 4 + lg];
            bfr[fo] = *(bf16x8*)&wv;
        }
        const uint4* buf = lds[kc & 1];
        #pragma unroll
        for (int nn = 0; nn < 4; ++nn) {
            int n_g = w * 4 + nn;
            uint4 a = buf[lr * 64 + ((n_g * 4 + lg) ^ (lr & 7))];
            bf16x8 af = *(bf16x8*)&a;
            #pragma unroll
            for (int fo = 0; fo < 4; ++fo)
                acc[nn][fo] = __builtin_amdgcn_mfma_f32_16x16x32_bf16(af, bfr[fo], acc[nn][fo], 0, 0, 0);
        }
        if (kc < KCH - 1) {
            uint4* buf2 = lds[(kc + 1) & 1];
            #pragma unroll
            for (int j = 0; j < 4; ++j) {
                int idx = j * 256 + t;
                int row = idx >> 6, c = idx & 63;
                buf2[row * 64 + (c ^ (row & 7))] = nreg[j];
            }
        }
        __syncthreads();
    }

    // epilogue: D row = lg*4+rr, col = fo*16+lr; nontemporal (write-once)
    #pragma unroll
    for (int nn = 0; nn < 4; ++nn) {
        int n_g = w * 4 + nn;
        #pragma unroll
        for (int fo = 0; fo < 4; ++fo) {
            float* op = out + ((size_t)n_g * M + m0 + lg * 4) * FOUT + fo * 16 + lr;
            #pragma unroll
            for (int rr = 0; rr < 4; ++rr)
                __builtin_nontemporal_store(fmaxf(acc[nn][fo][rr], 0.f), op + (size_t)rr * FOUT);
        }
    }
}

extern "C" void kernel_launch(void* const* d_in, const int* in_sizes, int n_in,
                              void* d_out, int out_size, void* d_ws, size_t ws_size,
                              hipStream_t stream) {
    const float* x         = (const float*)d_in[0];
    const float* edge_vals = (const float*)d_in[1];
    const float* dk        = (const float*)d_in[2];
    const float* pk        = (const float*)d_in[3];
    const float* bias      = (const float*)d_in[4];
    const int*   erow      = (const int*)d_in[5];
    const int*   ecol      = (const int*)d_in[6];
    float* out = (float*)d_out;

    const int M = M_NODES;
    const int E = in_sizes[1];

    // ws layout: 5 T buffers (bf16 [M][512]) | W | row_ptr | fill | edges
    size_t t_words = (size_t)M * 64;              // uint4 per T buffer
    uint4* T       = (uint4*)d_ws;                // T + k*t_words = T_k
    u16*   W       = (u16*)(T + 5 * t_words);
    int*   row_ptr = (int*)(W + FOUT * KCH * FIN);
    int*   fill    = row_ptr + (M + 1);
    int2*  edges   = (int2*)(fill + M);

    uint4* T0 = T;
    uint4* T1 = T + 1 * t_words;
    uint4* T2 = T + 2 * t_words;
    uint4* T3 = T + 3 * t_words;
    uint4* T4 = T + 4 * t_words;

    // CSR build (per call; no cached state)
    hipMemsetAsync(fill, 0, (size_t)M * sizeof(int), stream);
    count_kernel<<<(E + 255) / 256, 256, 0, stream>>>(erow, fill, E);
    scan_kernel<<<1, 1024, 0, stream>>>(fill, row_ptr, M);
    scatter_kernel<<<(E + 255) / 256, 256, 0, stream>>>(erow, ecol, edge_vals, fill, edges, E);

    // T0 = x^T (bf16); W = pk (*) dk
    cast_transpose_kernel<<<M / 4, 256, 0, stream>>>(x, T0, M);
    wprep_kernel<<<(FOUT * KCH * FIN + 255) / 256, 256, 0, stream>>>(dk, pk, W);

    // Chebyshev recursion
    spmm_kernel<1><<<M / 4, 256, 0, stream>>>(T0, T0, T1, row_ptr, edges, M);
    spmm_kernel<0><<<M / 4, 256, 0, stream>>>(T1, T0, T2, row_ptr, edges, M);
    spmm_kernel<0><<<M / 4, 256, 0, stream>>>(T2, T1, T3, row_ptr, edges, M);
    spmm_kernel<0><<<M / 4, 256, 0, stream>>>(T3, T2, T4, row_ptr, edges, M);

    // Fused depthwise+pointwise via MFMA, bias + relu epilogue
    pw_mfma_kernel<<<M / 16, 256, 0, stream>>>(T, (const uint4*)W, bias, out, M);
}

// Round 5
// 440.913 us; speedup vs baseline: 2.2751x; 1.0901x over previous
//
#include <hip/hip_runtime.h>

// GraphSeparableConv round 5:
//  - spmm: 8-deep gather batch (covers mean degree in one latency exposure),
//    Tprev prefetched before the edge loop
//  - scan: thread-serial (48 rows/thread) single block, int4-vectorized
//  - pw:   unchanged (LDS-staged, XOR-swizzled, double-buffered over kc)
// T_k layout: [M][512] bf16 (1KB rows), five buffers contiguous in ws.

#define M_NODES 49152
#define FIN 32
#define KCH 5
#define FOUT 64
#define NB 16

typedef unsigned int u32;
typedef unsigned short u16;
typedef short bf16x8 __attribute__((ext_vector_type(8)));
typedef float f32x4 __attribute__((ext_vector_type(4)));

__device__ __forceinline__ float bflo(u32 w) { union { float f; u32 i; } v; v.i = w << 16; return v.f; }
__device__ __forceinline__ float bfhi(u32 w) { union { float f; u32 i; } v; v.i = w & 0xffff0000u; return v.f; }
__device__ __forceinline__ u32 f2bf(float f) {
    union { float f; u32 i; } v; v.f = f;
    u32 r = v.i + 0x7fffu + ((v.i >> 16) & 1u);
    return r >> 16;
}
__device__ __forceinline__ u32 pack2(float a, float b) { return f2bf(a) | (f2bf(b) << 16); }

__global__ void count_kernel(const int* __restrict__ rows, int* __restrict__ cnt, int E) {
    int e = blockIdx.x * 256 + threadIdx.x;
    if (e < E) atomicAdd(&cnt[rows[e]], 1);
}

// Single block, 1024 threads, CH=M/1024 rows per thread (serial local scan).
// cf[i] -> exclusive prefix; row_ptr[0..M]; cf re-initialized to cursors.
__global__ __launch_bounds__(1024) void scan_kernel(int* __restrict__ cf,
                                                    int* __restrict__ row_ptr, int M) {
    const int CH = M_NODES / 1024;       // 48
    int tid = threadIdx.x;
    int lane = tid & 63;
    int wid = tid >> 6;
    int base = tid * CH;

    int4 v[CH / 4];
    const int4* src = (const int4*)(cf + base);
    int sum = 0;
    #pragma unroll
    for (int j = 0; j < CH / 4; ++j) {
        v[j] = src[j];
        sum += v[j].x + v[j].y + v[j].z + v[j].w;
    }
    // block exclusive scan of per-thread sums
    int x = sum;
    #pragma unroll
    for (int off = 1; off < 64; off <<= 1) {
        int y = __shfl_up(x, off, 64);
        if (lane >= off) x += y;
    }
    __shared__ int wsum[16];
    if (lane == 63) wsum[wid] = x;
    __syncthreads();
    if (tid < 16) {
        int w = wsum[tid];
        int xx = w;
        #pragma unroll
        for (int off = 1; off < 16; off <<= 1) {
            int y = __shfl_up(xx, off, 64);
            if (tid >= off) xx += y;
        }
        wsum[tid] = xx - w;
    }
    __syncthreads();
    int run = (x - sum) + wsum[wid];     // exclusive prefix for this thread
    int4* rp = (int4*)(row_ptr + base);
    int4* cc = (int4*)(cf + base);
    #pragma unroll
    for (int j = 0; j < CH / 4; ++j) {
        int4 o;
        o.x = run;           run += v[j].x;
        o.y = run;           run += v[j].y;
        o.z = run;           run += v[j].z;
        o.w = run;           run += v[j].w;
        rp[j] = o;
        cc[j] = o;
    }
    if (tid == 1023) row_ptr[M] = run;
}

__global__ void scatter_kernel(const int* __restrict__ rows, const int* __restrict__ cols,
                               const float* __restrict__ vals, int* __restrict__ fill,
                               int2* __restrict__ edges, int E) {
    int e = blockIdx.x * 256 + threadIdx.x;
    if (e < E) {
        int r = rows[e];
        int pos = atomicAdd(&fill[r], 1);
        int2 ed; ed.x = cols[e]; ed.y = __float_as_int(vals[e]);
        edges[pos] = ed;
    }
}

// x [N,M,Fin] f32 -> T0 [M][512] bf16.  Wave per row; lane covers 8 channels.
__global__ __launch_bounds__(256) void cast_transpose_kernel(
    const float* __restrict__ x, uint4* __restrict__ T0, int M) {
    int m = blockIdx.x * 4 + (threadIdx.x >> 6);
    int l = threadIdx.x & 63;
    int n = l >> 2;
    int f0 = (l & 3) * 8;
    const float4* xp = (const float4*)(x + ((size_t)n * M + m) * FIN + f0);
    float4 a = xp[0], b = xp[1];
    uint4 o;
    o.x = pack2(a.x, a.y); o.y = pack2(a.z, a.w);
    o.z = pack2(b.x, b.y); o.w = pack2(b.z, b.w);
    T0[(size_t)m * 64 + l] = o;
}

// W[fo][k*32+f] = bf16(pk[fo,f] * dk[f,k]) : 64 x 160 bf16
__global__ void wprep_kernel(const float* __restrict__ dk, const float* __restrict__ pk,
                             u16* __restrict__ W) {
    int t = blockIdx.x * 256 + threadIdx.x;
    if (t < FOUT * KCH * FIN) {
        int fo = t / (KCH * FIN);
        int kf = t % (KCH * FIN);
        int kc = kf / FIN;
        int f  = kf % FIN;
        W[fo * (KCH * FIN) + kf] = (u16)f2bf(pk[fo * FIN + f] * dk[f * KCH + kc]);
    }
}

__device__ __forceinline__ void acc8(float* r, uint4 g, float v) {
    r[0] = fmaf(v, bflo(g.x), r[0]); r[1] = fmaf(v, bfhi(g.x), r[1]);
    r[2] = fmaf(v, bflo(g.y), r[2]); r[3] = fmaf(v, bfhi(g.y), r[3]);
    r[4] = fmaf(v, bflo(g.z), r[4]); r[5] = fmaf(v, bfhi(g.z), r[5]);
    r[6] = fmaf(v, bflo(g.w), r[6]); r[7] = fmaf(v, bfhi(g.w), r[7]);
}

// Wave per row m, 8-deep gather batches; Tprev prefetched ahead of the loop.
// FIRST: T1 = L*T0.  else: T_k = 2*L*T_{k-1} - T_{k-2}.
template<int FIRST>
__global__ __launch_bounds__(256) void spmm_kernel(
    const uint4* __restrict__ Tin, const uint4* __restrict__ Tprev, uint4* __restrict__ Tout,
    const int* __restrict__ row_ptr, const int2* __restrict__ edges, int M) {
    int m = blockIdx.x * 4 + (threadIdx.x >> 6);
    int l = threadIdx.x & 63;
    int e = row_ptr[m];
    int e_end = row_ptr[m + 1];
    uint4 p;
    if (!FIRST) p = Tprev[(size_t)m * 64 + l];   // independent; hides under gathers
    float r[8] = {0.f, 0.f, 0.f, 0.f, 0.f, 0.f, 0.f, 0.f};
    for (; e + 8 <= e_end; e += 8) {
        int2 ed[8];
        #pragma unroll
        for (int j = 0; j < 8; ++j) ed[j] = edges[e + j];
        uint4 g[8];
        #pragma unroll
        for (int j = 0; j < 8; ++j) g[j] = Tin[(size_t)ed[j].x * 64 + l];
        #pragma unroll
        for (int j = 0; j < 8; ++j) acc8(r, g[j], __int_as_float(ed[j].y));
    }
    if (e + 4 <= e_end) {
        int2 ed[4];
        #pragma unroll
        for (int j = 0; j < 4; ++j) ed[j] = edges[e + j];
        uint4 g[4];
        #pragma unroll
        for (int j = 0; j < 4; ++j) g[j] = Tin[(size_t)ed[j].x * 64 + l];
        #pragma unroll
        for (int j = 0; j < 4; ++j) acc8(r, g[j], __int_as_float(ed[j].y));
        e += 4;
    }
    for (; e < e_end; ++e) {
        int2 ed = edges[e];
        uint4 g = Tin[(size_t)ed.x * 64 + l];
        acc8(r, g, __int_as_float(ed.y));
    }
    if (!FIRST) {
        r[0] = fmaf(2.f, r[0], -bflo(p.x)); r[1] = fmaf(2.f, r[1], -bfhi(p.x));
        r[2] = fmaf(2.f, r[2], -bflo(p.y)); r[3] = fmaf(2.f, r[3], -bfhi(p.y));
        r[4] = fmaf(2.f, r[4], -bflo(p.z)); r[5] = fmaf(2.f, r[5], -bfhi(p.z));
        r[6] = fmaf(2.f, r[6], -bflo(p.w)); r[7] = fmaf(2.f, r[7], -bfhi(p.w));
    }
    uint4 o;
    o.x = pack2(r[0], r[1]); o.y = pack2(r[2], r[3]);
    o.z = pack2(r[4], r[5]); o.w = pack2(r[6], r[7]);
    Tout[(size_t)m * 64 + l] = o;
}

// out[n,m,fo] = relu(bias[fo] + sum_{k,f} W[fo, k*32+f] * T_k[m, n*32+f])
// Block: 256 thr = 4 waves; block owns m-tile of 16 rows x all 16 n x 64 fo.
// Per kc: stage T_kc[m0..m0+15][:] (16KB) in LDS (XOR swizzle, double buffer);
// wave w handles n = 4w..4w+3, 4 fo-tiles each; acc[4][4] f32x4 over kc.
__global__ __launch_bounds__(256) void pw_mfma_kernel(
    const uint4* __restrict__ T, const uint4* __restrict__ W4,
    const float* __restrict__ bias, float* __restrict__ out, int M) {
    __shared__ uint4 lds[2][1024];
    int t = threadIdx.x;
    int w = t >> 6;
    int l = t & 63;
    int lr = l & 15;
    int lg = l >> 4;
    int m0 = blockIdx.x * 16;
    const size_t kstride = (size_t)M * 64;
    const uint4* tile_base = T + (size_t)m0 * 64;

    float bv[4];
    #pragma unroll
    for (int fo = 0; fo < 4; ++fo) bv[fo] = bias[fo * 16 + lr];

    f32x4 acc[4][4];
    #pragma unroll
    for (int nn = 0; nn < 4; ++nn)
        #pragma unroll
        for (int fo = 0; fo < 4; ++fo)
            acc[nn][fo] = (f32x4){bv[fo], bv[fo], bv[fo], bv[fo]};

    // prologue: stage kc=0
    uint4 sreg[4];
    #pragma unroll
    for (int j = 0; j < 4; ++j) sreg[j] = tile_base[(size_t)j * 256 + t];
    #pragma unroll
    for (int j = 0; j < 4; ++j) {
        int idx = j * 256 + t;
        int row = idx >> 6, c = idx & 63;
        lds[0][row * 64 + (c ^ (row & 7))] = sreg[j];
    }
    __syncthreads();

    for (int kc = 0; kc < KCH; ++kc) {
        uint4 nreg[4];
        if (kc < KCH - 1) {
            const uint4* src = tile_base + (size_t)(kc + 1) * kstride;
            #pragma unroll
            for (int j = 0; j < 4; ++j) nreg[j] = src[(size_t)j * 256 + t];
        }
        bf16x8 bfr[4];
        #pragma unroll
        for (int fo = 0; fo < 4; ++fo) {
            uint4 wv = W4[(fo * 16 + lr) * 20 + kc * 4 + lg];
            bfr[fo] = *(bf16x8*)&wv;
        }
        const uint4* buf = lds[kc & 1];
        #pragma unroll
        for (int nn = 0; nn < 4; ++nn) {
            int n_g = w * 4 + nn;
            uint4 a = buf[lr * 64 + ((n_g * 4 + lg) ^ (lr & 7))];
            bf16x8 af = *(bf16x8*)&a;
            #pragma unroll
            for (int fo = 0; fo < 4; ++fo)
                acc[nn][fo] = __builtin_amdgcn_mfma_f32_16x16x32_bf16(af, bfr[fo], acc[nn][fo], 0, 0, 0);
        }
        if (kc < KCH - 1) {
            uint4* buf2 = lds[(kc + 1) & 1];
            #pragma unroll
            for (int j = 0; j < 4; ++j) {
                int idx = j * 256 + t;
                int row = idx >> 6, c = idx & 63;
                buf2[row * 64 + (c ^ (row & 7))] = nreg[j];
            }
        }
        __syncthreads();
    }

    // epilogue: D row = lg*4+rr, col = fo*16+lr; nontemporal (write-once)
    #pragma unroll
    for (int nn = 0; nn < 4; ++nn) {
        int n_g = w * 4 + nn;
        #pragma unroll
        for (int fo = 0; fo < 4; ++fo) {
            float* op = out + ((size_t)n_g * M + m0 + lg * 4) * FOUT + fo * 16 + lr;
            #pragma unroll
            for (int rr = 0; rr < 4; ++rr)
                __builtin_nontemporal_store(fmaxf(acc[nn][fo][rr], 0.f), op + (size_t)rr * FOUT);
        }
    }
}

extern "C" void kernel_launch(void* const* d_in, const int* in_sizes, int n_in,
                              void* d_out, int out_size, void* d_ws, size_t ws_size,
                              hipStream_t stream) {
    const float* x         = (const float*)d_in[0];
    const float* edge_vals = (const float*)d_in[1];
    const float* dk        = (const float*)d_in[2];
    const float* pk        = (const float*)d_in[3];
    const float* bias      = (const float*)d_in[4];
    const int*   erow      = (const int*)d_in[5];
    const int*   ecol      = (const int*)d_in[6];
    float* out = (float*)d_out;

    const int M = M_NODES;
    const int E = in_sizes[1];

    // ws layout: 5 T buffers (bf16 [M][512]) | W | row_ptr | fill | edges
    size_t t_words = (size_t)M * 64;              // uint4 per T buffer
    uint4* T       = (uint4*)d_ws;                // T + k*t_words = T_k
    u16*   W       = (u16*)(T + 5 * t_words);
    int*   row_ptr = (int*)(W + FOUT * KCH * FIN);
    int*   fill    = row_ptr + (M + 4);           // keep int4 alignment
    int2*  edges   = (int2*)(fill + M);

    uint4* T0 = T;
    uint4* T1 = T + 1 * t_words;
    uint4* T2 = T + 2 * t_words;
    uint4* T3 = T + 3 * t_words;
    uint4* T4 = T + 4 * t_words;

    // CSR build (per call; no cached state)
    hipMemsetAsync(fill, 0, (size_t)M * sizeof(int), stream);
    count_kernel<<<(E + 255) / 256, 256, 0, stream>>>(erow, fill, E);
    scan_kernel<<<1, 1024, 0, stream>>>(fill, row_ptr, M);
    scatter_kernel<<<(E + 255) / 256, 256, 0, stream>>>(erow, ecol, edge_vals, fill, edges, E);

    // T0 = x^T (bf16); W = pk (*) dk
    cast_transpose_kernel<<<M / 4, 256, 0, stream>>>(x, T0, M);
    wprep_kernel<<<(FOUT * KCH * FIN + 255) / 256, 256, 0, stream>>>(dk, pk, W);

    // Chebyshev recursion
    spmm_kernel<1><<<M / 4, 256, 0, stream>>>(T0, T0, T1, row_ptr, edges, M);
    spmm_kernel<0><<<M / 4, 256, 0, stream>>>(T1, T0, T2, row_ptr, edges, M);
    spmm_kernel<0><<<M / 4, 256, 0, stream>>>(T2, T1, T3, row_ptr, edges, M);
    spmm_kernel<0><<<M / 4, 256, 0, stream>>>(T3, T2, T4, row_ptr, edges, M);

    // Fused depthwise+pointwise via MFMA, bias + relu epilogue
    pw_mfma_kernel<<<M / 16, 256, 0, stream>>>(T, (const uint4*)W, bias, out, M);
}

// Round 7
// 425.405 us; speedup vs baseline: 2.3580x; 1.0365x over previous
//
#include <hip/hip_runtime.h>

// GraphSeparableConv round 7 (= round 6 with nontemporal builtin fix):
//  - pw rebuilt: all 5 A-tiles staged upfront via global_load_lds (pre-swizzled
//    global source, linear LDS dest -> swizzled layout, guide m173 pattern),
//    ONE barrier, pure ds_read_b128+MFMA phase, f32x4 nontemporal stores via
//    LDS-transposed epilogue.
//  - transpose: nontemporal x loads (read-once; keep LLC for T).
//  - count/scatter: 4-edge vectorized.
//  - spmm unchanged (at LLC gather ceiling; fp8 ruled out by error model).
//  - nontemporal builtins use ext_vector types (HIP float4 class is rejected).

#define M_NODES 49152
#define FIN 32
#define KCH 5
#define FOUT 64
#define NB 16

typedef unsigned int u32;
typedef unsigned short u16;
typedef short bf16x8 __attribute__((ext_vector_type(8)));
typedef float f32x4 __attribute__((ext_vector_type(4)));

__device__ __forceinline__ float bflo(u32 w) { union { float f; u32 i; } v; v.i = w << 16; return v.f; }
__device__ __forceinline__ float bfhi(u32 w) { union { float f; u32 i; } v; v.i = w & 0xffff0000u; return v.f; }
__device__ __forceinline__ u32 f2bf(float f) {
    union { float f; u32 i; } v; v.f = f;
    u32 r = v.i + 0x7fffu + ((v.i >> 16) & 1u);
    return r >> 16;
}
__device__ __forceinline__ u32 pack2(float a, float b) { return f2bf(a) | (f2bf(b) << 16); }

// async global->LDS, 16B per lane; LDS dest wave-uniform base + lane*16
__device__ __forceinline__ void stage_row(const uint4* gsrc, uint4* ldst) {
    __builtin_amdgcn_global_load_lds(
        (const __attribute__((address_space(1))) unsigned int*)gsrc,
        (__attribute__((address_space(3))) unsigned int*)ldst, 16, 0, 0);
}

__global__ void count_kernel(const int* __restrict__ rows, int* __restrict__ cnt, int E4) {
    int e = blockIdx.x * 256 + threadIdx.x;
    if (e < E4) {
        int4 r = ((const int4*)rows)[e];
        atomicAdd(&cnt[r.x], 1);
        atomicAdd(&cnt[r.y], 1);
        atomicAdd(&cnt[r.z], 1);
        atomicAdd(&cnt[r.w], 1);
    }
}

// Single block, 1024 threads, CH=M/1024 rows per thread (serial local scan).
__global__ __launch_bounds__(1024) void scan_kernel(int* __restrict__ cf,
                                                    int* __restrict__ row_ptr, int M) {
    const int CH = M_NODES / 1024;       // 48
    int tid = threadIdx.x;
    int lane = tid & 63;
    int wid = tid >> 6;
    int base = tid * CH;

    int4 v[CH / 4];
    const int4* src = (const int4*)(cf + base);
    int sum = 0;
    #pragma unroll
    for (int j = 0; j < CH / 4; ++j) {
        v[j] = src[j];
        sum += v[j].x + v[j].y + v[j].z + v[j].w;
    }
    int x = sum;
    #pragma unroll
    for (int off = 1; off < 64; off <<= 1) {
        int y = __shfl_up(x, off, 64);
        if (lane >= off) x += y;
    }
    __shared__ int wsum[16];
    if (lane == 63) wsum[wid] = x;
    __syncthreads();
    if (tid < 16) {
        int w = wsum[tid];
        int xx = w;
        #pragma unroll
        for (int off = 1; off < 16; off <<= 1) {
            int y = __shfl_up(xx, off, 64);
            if (tid >= off) xx += y;
        }
        wsum[tid] = xx - w;
    }
    __syncthreads();
    int run = (x - sum) + wsum[wid];
    int4* rp = (int4*)(row_ptr + base);
    int4* cc = (int4*)(cf + base);
    #pragma unroll
    for (int j = 0; j < CH / 4; ++j) {
        int4 o;
        o.x = run;           run += v[j].x;
        o.y = run;           run += v[j].y;
        o.z = run;           run += v[j].z;
        o.w = run;           run += v[j].w;
        rp[j] = o;
        cc[j] = o;
    }
    if (tid == 1023) row_ptr[M] = run;
}

__global__ void scatter_kernel(const int* __restrict__ rows, const int* __restrict__ cols,
                               const float* __restrict__ vals, int* __restrict__ fill,
                               int2* __restrict__ edges, int E4) {
    int e = blockIdx.x * 256 + threadIdx.x;
    if (e < E4) {
        int4 r = ((const int4*)rows)[e];
        int4 c = ((const int4*)cols)[e];
        float4 v = ((const float4*)vals)[e];
        int pos;
        pos = atomicAdd(&fill[r.x], 1); edges[pos] = (int2){c.x, __float_as_int(v.x)};
        pos = atomicAdd(&fill[r.y], 1); edges[pos] = (int2){c.y, __float_as_int(v.y)};
        pos = atomicAdd(&fill[r.z], 1); edges[pos] = (int2){c.z, __float_as_int(v.z)};
        pos = atomicAdd(&fill[r.w], 1); edges[pos] = (int2){c.w, __float_as_int(v.w)};
    }
}

// x [N,M,Fin] f32 -> T0 [M][512] bf16.  Wave per row; lane covers 8 channels.
__global__ __launch_bounds__(256) void cast_transpose_kernel(
    const float* __restrict__ x, uint4* __restrict__ T0, int M) {
    int m = blockIdx.x * 4 + (threadIdx.x >> 6);
    int l = threadIdx.x & 63;
    int n = l >> 2;
    int f0 = (l & 3) * 8;
    const f32x4* xp = (const f32x4*)(x + ((size_t)n * M + m) * FIN + f0);
    f32x4 a = __builtin_nontemporal_load(xp);
    f32x4 b = __builtin_nontemporal_load(xp + 1);
    uint4 o;
    o.x = pack2(a[0], a[1]); o.y = pack2(a[2], a[3]);
    o.z = pack2(b[0], b[1]); o.w = pack2(b[2], b[3]);
    T0[(size_t)m * 64 + l] = o;
}

// W[fo][k*32+f] = bf16(pk[fo,f] * dk[f,k]) : 64 x 160 bf16
__global__ void wprep_kernel(const float* __restrict__ dk, const float* __restrict__ pk,
                             u16* __restrict__ W) {
    int t = blockIdx.x * 256 + threadIdx.x;
    if (t < FOUT * KCH * FIN) {
        int fo = t / (KCH * FIN);
        int kf = t % (KCH * FIN);
        int kc = kf / FIN;
        int f  = kf % FIN;
        W[fo * (KCH * FIN) + kf] = (u16)f2bf(pk[fo * FIN + f] * dk[f * KCH + kc]);
    }
}

__device__ __forceinline__ void acc8(float* r, uint4 g, float v) {
    r[0] = fmaf(v, bflo(g.x), r[0]); r[1] = fmaf(v, bfhi(g.x), r[1]);
    r[2] = fmaf(v, bflo(g.y), r[2]); r[3] = fmaf(v, bfhi(g.y), r[3]);
    r[4] = fmaf(v, bflo(g.z), r[4]); r[5] = fmaf(v, bfhi(g.z), r[5]);
    r[6] = fmaf(v, bflo(g.w), r[6]); r[7] = fmaf(v, bfhi(g.w), r[7]);
}

// Wave per row m, 8-deep gather batches; Tprev prefetched ahead of the loop.
template<int FIRST>
__global__ __launch_bounds__(256) void spmm_kernel(
    const uint4* __restrict__ Tin, const uint4* __restrict__ Tprev, uint4* __restrict__ Tout,
    const int* __restrict__ row_ptr, const int2* __restrict__ edges, int M) {
    int m = blockIdx.x * 4 + (threadIdx.x >> 6);
    int l = threadIdx.x & 63;
    int e = row_ptr[m];
    int e_end = row_ptr[m + 1];
    uint4 p;
    if (!FIRST) p = Tprev[(size_t)m * 64 + l];
    float r[8] = {0.f, 0.f, 0.f, 0.f, 0.f, 0.f, 0.f, 0.f};
    for (; e + 8 <= e_end; e += 8) {
        int2 ed[8];
        #pragma unroll
        for (int j = 0; j < 8; ++j) ed[j] = edges[e + j];
        uint4 g[8];
        #pragma unroll
        for (int j = 0; j < 8; ++j) g[j] = Tin[(size_t)ed[j].x * 64 + l];
        #pragma unroll
        for (int j = 0; j < 8; ++j) acc8(r, g[j], __int_as_float(ed[j].y));
    }
    if (e + 4 <= e_end) {
        int2 ed[4];
        #pragma unroll
        for (int j = 0; j < 4; ++j) ed[j] = edges[e + j];
        uint4 g[4];
        #pragma unroll
        for (int j = 0; j < 4; ++j) g[j] = Tin[(size_t)ed[j].x * 64 + l];
        #pragma unroll
        for (int j = 0; j < 4; ++j) acc8(r, g[j], __int_as_float(ed[j].y));
        e += 4;
    }
    for (; e < e_end; ++e) {
        int2 ed = edges[e];
        uint4 g = Tin[(size_t)ed.x * 64 + l];
        acc8(r, g, __int_as_float(ed.y));
    }
    if (!FIRST) {
        r[0] = fmaf(2.f, r[0], -bflo(p.x)); r[1] = fmaf(2.f, r[1], -bfhi(p.x));
        r[2] = fmaf(2.f, r[2], -bflo(p.y)); r[3] = fmaf(2.f, r[3], -bfhi(p.y));
        r[4] = fmaf(2.f, r[4], -bflo(p.z)); r[5] = fmaf(2.f, r[5], -bfhi(p.z));
        r[6] = fmaf(2.f, r[6], -bflo(p.w)); r[7] = fmaf(2.f, r[7], -bfhi(p.w));
    }
    uint4 o;
    o.x = pack2(r[0], r[1]); o.y = pack2(r[2], r[3]);
    o.z = pack2(r[4], r[5]); o.w = pack2(r[6], r[7]);
    Tout[(size_t)m * 64 + l] = o;
}

// out[n,m,fo] = relu(bias[fo] + sum_{k,f} W[fo,k*32+f] * T_k[m, n*32+f])
// Block = 16 m-rows x all 16 n x 64 fo; 4 waves, wave w owns n = 4w..4w+3.
// Phase 1: stage 5 tiles (16 rows x 64 uint4 each, 80KB) via global_load_lds.
//   LDS dest linear; global source col pre-swizzled: col_src = lane ^ (row&7)
//   => lds[row][c] = data[row][c ^ (row&7)]  (2-way bank on read = free).
// Phase 2 (one barrier): 20 ds_read_b128 + 80 MFMA per wave; acc init = bias.
// Phase 3 (one barrier): per-wave LDS transpose of acc -> f32x4 nt stores.
__global__ __launch_bounds__(256) void pw_mfma_kernel(
    const uint4* __restrict__ T, const uint4* __restrict__ W4,
    const float* __restrict__ bias, float* __restrict__ out, int M) {
    __shared__ uint4 lds4[5 * 1024];   // 80 KB
    int t = threadIdx.x;
    int w = t >> 6;
    int l = t & 63;
    int lr = l & 15;
    int lg = l >> 4;
    int m0 = blockIdx.x * 16;
    const size_t kstride = (size_t)M * 64;

    // W fragments + bias (issued first; latency hidden under staging)
    bf16x8 bfr[KCH][4];
    #pragma unroll
    for (int kc = 0; kc < KCH; ++kc)
        #pragma unroll
        for (int fo = 0; fo < 4; ++fo) {
            uint4 wv = W4[(fo * 16 + lr) * 20 + kc * 4 + lg];
            bfr[kc][fo] = *(bf16x8*)&wv;
        }
    f32x4 acc[4][4];
    #pragma unroll
    for (int fo = 0; fo < 4; ++fo) {
        float bv = bias[fo * 16 + lr];
        #pragma unroll
        for (int nn = 0; nn < 4; ++nn)
            acc[nn][fo] = (f32x4){bv, bv, bv, bv};
    }

    // Phase 1: stage all 5 tiles; wave w stages rows 4w..4w+3 of each tile
    #pragma unroll
    for (int kc = 0; kc < KCH; ++kc) {
        #pragma unroll
        for (int i = 0; i < 4; ++i) {
            int row = w * 4 + i;
            const uint4* gsrc = T + (size_t)kc * kstride + (size_t)(m0 + row) * 64
                                  + (l ^ (row & 7));
            stage_row(gsrc, &lds4[kc * 1024 + row * 64]);
        }
    }
    __syncthreads();   // compiler drains vmcnt(0) before barrier

    // Phase 2: pure LDS + MFMA
    #pragma unroll
    for (int kc = 0; kc < KCH; ++kc) {
        #pragma unroll
        for (int nn = 0; nn < 4; ++nn) {
            int n = w * 4 + nn;
            uint4 a = lds4[kc * 1024 + lr * 64 + ((n * 4 + lg) ^ (lr & 7))];
            bf16x8 af = *(bf16x8*)&a;
            #pragma unroll
            for (int fo = 0; fo < 4; ++fo)
                acc[nn][fo] = __builtin_amdgcn_mfma_f32_16x16x32_bf16(af, bfr[kc][fo], acc[nn][fo], 0, 0, 0);
        }
    }
    __syncthreads();   // tiles dead; reuse LDS for epilogue transpose

    // Phase 3: per-wave transpose (zone [16][68] f32), f32x4 nt stores
    float* zone = (float*)lds4 + w * 1088;
    #pragma unroll
    for (int nn = 0; nn < 4; ++nn) {
        int n = w * 4 + nn;
        #pragma unroll
        for (int fo = 0; fo < 4; ++fo)
            #pragma unroll
            for (int rr = 0; rr < 4; ++rr)
                zone[(lg * 4 + rr) * 68 + fo * 16 + lr] = acc[nn][fo][rr];
        // lane l -> mrow = i*4 + (l>>4), col4 = l&15
        #pragma unroll
        for (int i = 0; i < 4; ++i) {
            int mrow = i * 4 + lg;
            f32x4 v = *(const f32x4*)&zone[mrow * 68 + lr * 4];
            v[0] = fmaxf(v[0], 0.f); v[1] = fmaxf(v[1], 0.f);
            v[2] = fmaxf(v[2], 0.f); v[3] = fmaxf(v[3], 0.f);
            f32x4* op = (f32x4*)(out + ((size_t)n * M + m0 + mrow) * FOUT + lr * 4);
            __builtin_nontemporal_store(v, op);
        }
    }
}

extern "C" void kernel_launch(void* const* d_in, const int* in_sizes, int n_in,
                              void* d_out, int out_size, void* d_ws, size_t ws_size,
                              hipStream_t stream) {
    const float* x         = (const float*)d_in[0];
    const float* edge_vals = (const float*)d_in[1];
    const float* dk        = (const float*)d_in[2];
    const float* pk        = (const float*)d_in[3];
    const float* bias      = (const float*)d_in[4];
    const int*   erow      = (const int*)d_in[5];
    const int*   ecol      = (const int*)d_in[6];
    float* out = (float*)d_out;

    const int M = M_NODES;
    const int E = in_sizes[1];

    // ws layout: 5 T buffers (bf16 [M][512]) | W | row_ptr | fill | edges
    size_t t_words = (size_t)M * 64;              // uint4 per T buffer
    uint4* T       = (uint4*)d_ws;                // T + k*t_words = T_k
    u16*   W       = (u16*)(T + 5 * t_words);
    int*   row_ptr = (int*)(W + FOUT * KCH * FIN);
    int*   fill    = row_ptr + (M + 4);           // keep int4 alignment
    int2*  edges   = (int2*)(fill + M);

    uint4* T0 = T;
    uint4* T1 = T + 1 * t_words;
    uint4* T2 = T + 2 * t_words;
    uint4* T3 = T + 3 * t_words;
    uint4* T4 = T + 4 * t_words;

    // CSR build (per call; no cached state)
    hipMemsetAsync(fill, 0, (size_t)M * sizeof(int), stream);
    count_kernel<<<(E / 4 + 255) / 256, 256, 0, stream>>>(erow, fill, E / 4);
    scan_kernel<<<1, 1024, 0, stream>>>(fill, row_ptr, M);
    scatter_kernel<<<(E / 4 + 255) / 256, 256, 0, stream>>>(erow, ecol, edge_vals, fill, edges, E / 4);

    // T0 = x^T (bf16); W = pk (*) dk
    cast_transpose_kernel<<<M / 4, 256, 0, stream>>>(x, T0, M);
    wprep_kernel<<<(FOUT * KCH * FIN + 255) / 256, 256, 0, stream>>>(dk, pk, W);

    // Chebyshev recursion
    spmm_kernel<1><<<M / 4, 256, 0, stream>>>(T0, T0, T1, row_ptr, edges, M);
    spmm_kernel<0><<<M / 4, 256, 0, stream>>>(T1, T0, T2, row_ptr, edges, M);
    spmm_kernel<0><<<M / 4, 256, 0, stream>>>(T2, T1, T3, row_ptr, edges, M);
    spmm_kernel<0><<<M / 4, 256, 0, stream>>>(T3, T2, T4, row_ptr, edges, M);

    // Fused depthwise+pointwise via MFMA, bias + relu epilogue
    pw_mfma_kernel<<<M / 16, 256, 0, stream>>>(T, (const uint4*)W, bias, out, M);
}

// Round 8
// 415.839 us; speedup vs baseline: 2.4123x; 1.0230x over previous
//
#include <hip/hip_runtime.h>

// GraphSeparableConv round 8:
//  - spmm: 2 rows per wave with interleaved gather issue (16 outstanding 1KB
//    gathers/wave, was 8); edge descriptors via wave-uniform (scalar) loads.
//  - CSR replaced by ELL32: scatter with atomic cursors builds ell[M][32] +
//    deg[M]; count & scan kernels deleted.
//  - pw / transpose / wprep unchanged (round-7 verified).
// T_k layout: [M][512] bf16 (1KB rows), five buffers contiguous in ws.

#define M_NODES 49152
#define FIN 32
#define KCH 5
#define FOUT 64
#define NB 16

typedef unsigned int u32;
typedef unsigned short u16;
typedef short bf16x8 __attribute__((ext_vector_type(8)));
typedef float f32x4 __attribute__((ext_vector_type(4)));

__device__ __forceinline__ float bflo(u32 w) { union { float f; u32 i; } v; v.i = w << 16; return v.f; }
__device__ __forceinline__ float bfhi(u32 w) { union { float f; u32 i; } v; v.i = w & 0xffff0000u; return v.f; }
__device__ __forceinline__ u32 f2bf(float f) {
    union { float f; u32 i; } v; v.f = f;
    u32 r = v.i + 0x7fffu + ((v.i >> 16) & 1u);
    return r >> 16;
}
__device__ __forceinline__ u32 pack2(float a, float b) { return f2bf(a) | (f2bf(b) << 16); }

// async global->LDS, 16B per lane; LDS dest wave-uniform base + lane*16
__device__ __forceinline__ void stage_row(const uint4* gsrc, uint4* ldst) {
    __builtin_amdgcn_global_load_lds(
        (const __attribute__((address_space(1))) unsigned int*)gsrc,
        (__attribute__((address_space(3))) unsigned int*)ldst, 16, 0, 0);
}

// ELL32 build: atomic per-row cursors; deg = final counter value.
__global__ void scatter_kernel(const int* __restrict__ rows, const int* __restrict__ cols,
                               const float* __restrict__ vals, int* __restrict__ cnt,
                               int2* __restrict__ ell, int E4) {
    int e = blockIdx.x * 256 + threadIdx.x;
    if (e < E4) {
        int4 r = ((const int4*)rows)[e];
        int4 c = ((const int4*)cols)[e];
        float4 v = ((const float4*)vals)[e];
        int pos;
        pos = atomicAdd(&cnt[r.x], 1); if (pos < 32) ell[(size_t)r.x * 32 + pos] = (int2){c.x, __float_as_int(v.x)};
        pos = atomicAdd(&cnt[r.y], 1); if (pos < 32) ell[(size_t)r.y * 32 + pos] = (int2){c.y, __float_as_int(v.y)};
        pos = atomicAdd(&cnt[r.z], 1); if (pos < 32) ell[(size_t)r.z * 32 + pos] = (int2){c.z, __float_as_int(v.z)};
        pos = atomicAdd(&cnt[r.w], 1); if (pos < 32) ell[(size_t)r.w * 32 + pos] = (int2){c.w, __float_as_int(v.w)};
    }
}

// x [N,M,Fin] f32 -> T0 [M][512] bf16.  Wave per row; lane covers 8 channels.
__global__ __launch_bounds__(256) void cast_transpose_kernel(
    const float* __restrict__ x, uint4* __restrict__ T0, int M) {
    int m = blockIdx.x * 4 + (threadIdx.x >> 6);
    int l = threadIdx.x & 63;
    int n = l >> 2;
    int f0 = (l & 3) * 8;
    const f32x4* xp = (const f32x4*)(x + ((size_t)n * M + m) * FIN + f0);
    f32x4 a = __builtin_nontemporal_load(xp);
    f32x4 b = __builtin_nontemporal_load(xp + 1);
    uint4 o;
    o.x = pack2(a[0], a[1]); o.y = pack2(a[2], a[3]);
    o.z = pack2(b[0], b[1]); o.w = pack2(b[2], b[3]);
    T0[(size_t)m * 64 + l] = o;
}

// W[fo][k*32+f] = bf16(pk[fo,f] * dk[f,k]) : 64 x 160 bf16
__global__ void wprep_kernel(const float* __restrict__ dk, const float* __restrict__ pk,
                             u16* __restrict__ W) {
    int t = blockIdx.x * 256 + threadIdx.x;
    if (t < FOUT * KCH * FIN) {
        int fo = t / (KCH * FIN);
        int kf = t % (KCH * FIN);
        int kc = kf / FIN;
        int f  = kf % FIN;
        W[fo * (KCH * FIN) + kf] = (u16)f2bf(pk[fo * FIN + f] * dk[f * KCH + kc]);
    }
}

__device__ __forceinline__ void acc8(float* r, uint4 g, float v) {
    r[0] = fmaf(v, bflo(g.x), r[0]); r[1] = fmaf(v, bfhi(g.x), r[1]);
    r[2] = fmaf(v, bflo(g.y), r[2]); r[3] = fmaf(v, bfhi(g.y), r[3]);
    r[4] = fmaf(v, bflo(g.z), r[4]); r[5] = fmaf(v, bfhi(g.z), r[5]);
    r[6] = fmaf(v, bflo(g.w), r[6]); r[7] = fmaf(v, bfhi(g.w), r[7]);
}

// Two rows per wave, interleaved gather issue (up to 16 outstanding 1KB
// gathers).  Row indices wave-uniform (readfirstlane) -> scalar desc loads.
// FIRST: T1 = L*T0.  else: T_k = 2*L*T_{k-1} - T_{k-2}.
template<int FIRST>
__global__ __launch_bounds__(256) void spmm_kernel(
    const uint4* __restrict__ Tin, const uint4* __restrict__ Tprev, uint4* __restrict__ Tout,
    const int* __restrict__ deg, const int2* __restrict__ ell, int M) {
    int w = __builtin_amdgcn_readfirstlane((int)(threadIdx.x >> 6));
    int l = threadIdx.x & 63;
    int rA = blockIdx.x * 8 + w * 2;
    int rB = rA + 1;
    int dA = deg[rA]; if (dA > 32) dA = 32;
    int dB = deg[rB]; if (dB > 32) dB = 32;
    const int2* eA = ell + (size_t)rA * 32;
    const int2* eB = ell + (size_t)rB * 32;
    uint4 pA, pB;
    if (!FIRST) {
        pA = Tprev[(size_t)rA * 64 + l];
        pB = Tprev[(size_t)rB * 64 + l];
    }
    float a[8] = {0.f, 0.f, 0.f, 0.f, 0.f, 0.f, 0.f, 0.f};
    float b[8] = {0.f, 0.f, 0.f, 0.f, 0.f, 0.f, 0.f, 0.f};
    int dmax = dA > dB ? dA : dB;
    for (int s = 0; s < dmax; s += 8) {
        int cA = dA - s, cB = dB - s;
        int2 edA[8], edB[8];
        uint4 gA[8], gB[8];
        #pragma unroll
        for (int j = 0; j < 8; ++j) if (j < cA) edA[j] = eA[s + j];
        #pragma unroll
        for (int j = 0; j < 8; ++j) if (j < cB) edB[j] = eB[s + j];
        #pragma unroll
        for (int j = 0; j < 8; ++j) if (j < cA) gA[j] = Tin[(size_t)edA[j].x * 64 + l];
        #pragma unroll
        for (int j = 0; j < 8; ++j) if (j < cB) gB[j] = Tin[(size_t)edB[j].x * 64 + l];
        #pragma unroll
        for (int j = 0; j < 8; ++j) if (j < cA) acc8(a, gA[j], __int_as_float(edA[j].y));
        #pragma unroll
        for (int j = 0; j < 8; ++j) if (j < cB) acc8(b, gB[j], __int_as_float(edB[j].y));
    }
    if (!FIRST) {
        a[0] = fmaf(2.f, a[0], -bflo(pA.x)); a[1] = fmaf(2.f, a[1], -bfhi(pA.x));
        a[2] = fmaf(2.f, a[2], -bflo(pA.y)); a[3] = fmaf(2.f, a[3], -bfhi(pA.y));
        a[4] = fmaf(2.f, a[4], -bflo(pA.z)); a[5] = fmaf(2.f, a[5], -bfhi(pA.z));
        a[6] = fmaf(2.f, a[6], -bflo(pA.w)); a[7] = fmaf(2.f, a[7], -bfhi(pA.w));
        b[0] = fmaf(2.f, b[0], -bflo(pB.x)); b[1] = fmaf(2.f, b[1], -bfhi(pB.x));
        b[2] = fmaf(2.f, b[2], -bflo(pB.y)); b[3] = fmaf(2.f, b[3], -bfhi(pB.y));
        b[4] = fmaf(2.f, b[4], -bflo(pB.z)); b[5] = fmaf(2.f, b[5], -bfhi(pB.z));
        b[6] = fmaf(2.f, b[6], -bflo(pB.w)); b[7] = fmaf(2.f, b[7], -bfhi(pB.w));
    }
    uint4 oA, oB;
    oA.x = pack2(a[0], a[1]); oA.y = pack2(a[2], a[3]);
    oA.z = pack2(a[4], a[5]); oA.w = pack2(a[6], a[7]);
    oB.x = pack2(b[0], b[1]); oB.y = pack2(b[2], b[3]);
    oB.z = pack2(b[4], b[5]); oB.w = pack2(b[6], b[7]);
    Tout[(size_t)rA * 64 + l] = oA;
    Tout[(size_t)rB * 64 + l] = oB;
}

// out[n,m,fo] = relu(bias[fo] + sum_{k,f} W[fo,k*32+f] * T_k[m, n*32+f])
// Block = 16 m-rows x all 16 n x 64 fo; 4 waves, wave w owns n = 4w..4w+3.
// Phase 1: stage 5 tiles (16 rows x 64 uint4 each, 80KB) via global_load_lds
//   (pre-swizzled global source, linear LDS dest).
// Phase 2 (one barrier): 20 ds_read_b128 + 80 MFMA per wave; acc init = bias.
// Phase 3 (one barrier): per-wave LDS transpose of acc -> f32x4 nt stores.
__global__ __launch_bounds__(256) void pw_mfma_kernel(
    const uint4* __restrict__ T, const uint4* __restrict__ W4,
    const float* __restrict__ bias, float* __restrict__ out, int M) {
    __shared__ uint4 lds4[5 * 1024];   // 80 KB
    int t = threadIdx.x;
    int w = t >> 6;
    int l = t & 63;
    int lr = l & 15;
    int lg = l >> 4;
    int m0 = blockIdx.x * 16;
    const size_t kstride = (size_t)M * 64;

    // W fragments + bias (issued first; latency hidden under staging)
    bf16x8 bfr[KCH][4];
    #pragma unroll
    for (int kc = 0; kc < KCH; ++kc)
        #pragma unroll
        for (int fo = 0; fo < 4; ++fo) {
            uint4 wv = W4[(fo * 16 + lr) * 20 + kc * 4 + lg];
            bfr[kc][fo] = *(bf16x8*)&wv;
        }
    f32x4 acc[4][4];
    #pragma unroll
    for (int fo = 0; fo < 4; ++fo) {
        float bv = bias[fo * 16 + lr];
        #pragma unroll
        for (int nn = 0; nn < 4; ++nn)
            acc[nn][fo] = (f32x4){bv, bv, bv, bv};
    }

    // Phase 1: stage all 5 tiles; wave w stages rows 4w..4w+3 of each tile
    #pragma unroll
    for (int kc = 0; kc < KCH; ++kc) {
        #pragma unroll
        for (int i = 0; i < 4; ++i) {
            int row = w * 4 + i;
            const uint4* gsrc = T + (size_t)kc * kstride + (size_t)(m0 + row) * 64
                                  + (l ^ (row & 7));
            stage_row(gsrc, &lds4[kc * 1024 + row * 64]);
        }
    }
    __syncthreads();   // compiler drains vmcnt(0) before barrier

    // Phase 2: pure LDS + MFMA
    #pragma unroll
    for (int kc = 0; kc < KCH; ++kc) {
        #pragma unroll
        for (int nn = 0; nn < 4; ++nn) {
            int n = w * 4 + nn;
            uint4 a = lds4[kc * 1024 + lr * 64 + ((n * 4 + lg) ^ (lr & 7))];
            bf16x8 af = *(bf16x8*)&a;
            #pragma unroll
            for (int fo = 0; fo < 4; ++fo)
                acc[nn][fo] = __builtin_amdgcn_mfma_f32_16x16x32_bf16(af, bfr[kc][fo], acc[nn][fo], 0, 0, 0);
        }
    }
    __syncthreads();   // tiles dead; reuse LDS for epilogue transpose

    // Phase 3: per-wave transpose (zone [16][68] f32), f32x4 nt stores
    float* zone = (float*)lds4 + w * 1088;
    #pragma unroll
    for (int nn = 0; nn < 4; ++nn) {
        int n = w * 4 + nn;
        #pragma unroll
        for (int fo = 0; fo < 4; ++fo)
            #pragma unroll
            for (int rr = 0; rr < 4; ++rr)
                zone[(lg * 4 + rr) * 68 + fo * 16 + lr] = acc[nn][fo][rr];
        #pragma unroll
        for (int i = 0; i < 4; ++i) {
            int mrow = i * 4 + lg;
            f32x4 v = *(const f32x4*)&zone[mrow * 68 + lr * 4];
            v[0] = fmaxf(v[0], 0.f); v[1] = fmaxf(v[1], 0.f);
            v[2] = fmaxf(v[2], 0.f); v[3] = fmaxf(v[3], 0.f);
            f32x4* op = (f32x4*)(out + ((size_t)n * M + m0 + mrow) * FOUT + lr * 4);
            __builtin_nontemporal_store(v, op);
        }
    }
}

extern "C" void kernel_launch(void* const* d_in, const int* in_sizes, int n_in,
                              void* d_out, int out_size, void* d_ws, size_t ws_size,
                              hipStream_t stream) {
    const float* x         = (const float*)d_in[0];
    const float* edge_vals = (const float*)d_in[1];
    const float* dk        = (const float*)d_in[2];
    const float* pk        = (const float*)d_in[3];
    const float* bias      = (const float*)d_in[4];
    const int*   erow      = (const int*)d_in[5];
    const int*   ecol      = (const int*)d_in[6];
    float* out = (float*)d_out;

    const int M = M_NODES;
    const int E = in_sizes[1];

    // ws layout: 5 T buffers (bf16 [M][512]) | W | deg | ell
    size_t t_words = (size_t)M * 64;              // uint4 per T buffer
    uint4* T    = (uint4*)d_ws;                   // T + k*t_words = T_k
    u16*   W    = (u16*)(T + 5 * t_words);
    int*   deg  = (int*)(W + FOUT * KCH * FIN);
    int2*  ell  = (int2*)(deg + M);

    uint4* T0 = T;
    uint4* T1 = T + 1 * t_words;
    uint4* T2 = T + 2 * t_words;
    uint4* T3 = T + 3 * t_words;
    uint4* T4 = T + 4 * t_words;

    // ELL32 build (per call; no cached state)
    hipMemsetAsync(deg, 0, (size_t)M * sizeof(int), stream);
    scatter_kernel<<<(E / 4 + 255) / 256, 256, 0, stream>>>(erow, ecol, edge_vals, deg, ell, E / 4);

    // T0 = x^T (bf16); W = pk (*) dk
    cast_transpose_kernel<<<M / 4, 256, 0, stream>>>(x, T0, M);
    wprep_kernel<<<(FOUT * KCH * FIN + 255) / 256, 256, 0, stream>>>(dk, pk, W);

    // Chebyshev recursion (2 rows/wave, 8 rows/block)
    spmm_kernel<1><<<M / 8, 256, 0, stream>>>(T0, T0, T1, deg, ell, M);
    spmm_kernel<0><<<M / 8, 256, 0, stream>>>(T1, T0, T2, deg, ell, M);
    spmm_kernel<0><<<M / 8, 256, 0, stream>>>(T2, T1, T3, deg, ell, M);
    spmm_kernel<0><<<M / 8, 256, 0, stream>>>(T3, T2, T4, deg, ell, M);

    // Fused depthwise+pointwise via MFMA, bias + relu epilogue
    pw_mfma_kernel<<<M / 16, 256, 0, stream>>>(T, (const uint4*)W, bias, out, M);
}